// Round 1
// baseline (442.190 us; speedup 1.0000x reference)
//
#include <hip/hip_runtime.h>
#include <stdint.h>

// SelfAttention B=2,S=4096,E=1024,H=1024. f32 in, f32 out, bf16 MFMA inside.
// R8: all three GEMMs rewritten on a deep-pipelined K-loop (T3+T4+T5):
//     BK=32, 4 LDS buffers, 3 K-tiles in flight, counted s_waitcnt vmcnt(2L)
//     (never 0 in steady state), ONE raw s_barrier per K-tile, setprio(1)
//     around the MFMA cluster. 256-wide tiles, 512 thr / 8 waves, grids
//     exactly CU-wave-aligned (512/256/768 blocks). BK=32 natural LDS layout
//     is bank-conflict-free (bank-group=(4r+c)&7) -> no XOR swizzle needed.
// R7: softmax folded into GEMM epilogues (exp no-max is safe: scores ~N(0,1)).

typedef __bf16 bf16;
typedef __attribute__((ext_vector_type(4))) __bf16 bf16x4;
typedef __attribute__((ext_vector_type(8))) __bf16 bf16x8;
typedef __attribute__((ext_vector_type(4))) float f32x4;

__device__ __forceinline__ void g2l16(const void* g, void* l) {
  __builtin_amdgcn_global_load_lds(
      (const __attribute__((address_space(1))) uint32_t*)g,
      (__attribute__((address_space(3))) uint32_t*)l, 16, 0, 0);
}

template <int N> __device__ __forceinline__ void waitvm() {
  static_assert(N == 0 || N == 3 || N == 4 || N == 6 || N == 8, "vmcnt");
  if constexpr (N == 0) asm volatile("s_waitcnt vmcnt(0)" ::: "memory");
  else if constexpr (N == 3) asm volatile("s_waitcnt vmcnt(3)" ::: "memory");
  else if constexpr (N == 4) asm volatile("s_waitcnt vmcnt(4)" ::: "memory");
  else if constexpr (N == 6) asm volatile("s_waitcnt vmcnt(6)" ::: "memory");
  else asm volatile("s_waitcnt vmcnt(8)" ::: "memory");
}
template <int V> struct IC { static constexpr int value = V; };

// ---------------- f32 -> bf16 converters -----------------------------------
__global__ __launch_bounds__(256) void cvt_f32_bf16(
    const float* __restrict__ src, bf16* __restrict__ dst, int n) {
  const int i = (blockIdx.x * 256 + threadIdx.x) * 8;
  if (i >= n) return;
  f32x4 a = *(const f32x4*)(src + i);
  f32x4 b = *(const f32x4*)(src + i + 4);
  bf16x8 o;
#pragma unroll
  for (int e = 0; e < 4; ++e) { o[e] = (bf16)a[e]; o[4 + e] = (bf16)b[e]; }
  *(bf16x8*)(dst + i) = o;
}

__global__ __launch_bounds__(256) void cvt_w3(
    const float* __restrict__ Wq, const float* __restrict__ Wk,
    const float* __restrict__ Wv, bf16* __restrict__ dst) {
  const int i = (blockIdx.x * 256 + threadIdx.x) * 8;
  const int seg = i >> 20;
  const int off = i & 1048575;
  const float* src = (seg == 0) ? Wq : (seg == 1) ? Wk : Wv;
  f32x4 a = *(const f32x4*)(src + off);
  f32x4 b = *(const f32x4*)(src + off + 4);
  bf16x8 o;
#pragma unroll
  for (int e = 0; e < 4; ++e) { o[e] = (bf16)a[e]; o[4 + e] = (bf16)b[e]; }
  *(bf16x8*)(dst + i) = o;
}

// ---------------- deep-pipelined GEMM K-loop -------------------------------
// A:[BM][K], B:[BN][K] row-major (B pre-transposed), acc += A * B^T frags.
// 512 threads = 8 waves arranged WM x WN; per-wave tile (BM/WM) x (BN/WN).
// LDS: 4 buffers of (A: BM x 32, B: BN x 32) bf16. 3 K-tiles prefetched.
// Safety: buffers {t..t+3}&3 are distinct; reads of tile t-1 retire before
// each wave's lgkmcnt(0) in body(t-1), which precedes barrier(t), so staging
// tile t+3 (over t-1's buffer) after barrier(t) is WAR-safe. vmcnt(2L) +
// barrier(t) proves all waves' tile-t loads have landed before ds_reads.
template <int BM, int BN, int WM, int WN, int NT>
__device__ __forceinline__ void kloop(
    const bf16* __restrict__ Ag, const bf16* __restrict__ Bg, const int K,
    bf16* lds, f32x4 (&acc)[BM / WM / 16][BN / WN / 16]) {
  constexpr int L = (BM + BN) / 128;  // g2l16 per thread per K-tile
  constexpr int MR = BM / WM / 16, NR = BN / WN / 16;
  const int tid = threadIdx.x;
  const int lane = tid & 63, wave = tid >> 6;
  const int l15 = lane & 15, quad = lane >> 4;
  const int wrow = (wave / WN) * (BM / WM);
  const int wcol = (wave % WN) * (BN / WN);
  const int srow = tid >> 2;          // staging row 0..127
  const int scol = (tid & 3) * 8;     // staging 16B chunk within 32-elem row

  auto stage = [&](int t) {
    bf16* la = lds + (t & 3) * ((BM + BN) * 32);
    bf16* lb = la + BM * 32;
    const bf16* ga = Ag + (size_t)srow * K + t * 32 + scol;
    const bf16* gb = Bg + (size_t)srow * K + t * 32 + scol;
#pragma unroll
    for (int r = 0; r < BM / 128; ++r)
      g2l16(ga + (size_t)(r * 128) * K, la + (srow + r * 128) * 32 + scol);
#pragma unroll
    for (int r = 0; r < BN / 128; ++r)
      g2l16(gb + (size_t)(r * 128) * K, lb + (srow + r * 128) * 32 + scol);
  };

  stage(0);
  stage(1);
  stage(2);

  auto body = [&](int t, auto vm, bool do_stage) {
    waitvm<decltype(vm)::value>();      // tile t landed (own loads)
    __builtin_amdgcn_s_barrier();       // ...landed for ALL waves
    if (do_stage) stage(t + 3);         // issue next loads; stay in flight
    const bf16* la = lds + (t & 3) * ((BM + BN) * 32);
    const bf16* lb = la + BM * 32;
    bf16x8 af[MR], bq[NR];
#pragma unroll
    for (int i = 0; i < MR; ++i)
      af[i] = *(const bf16x8*)&la[(wrow + i * 16 + l15) * 32 + quad * 8];
#pragma unroll
    for (int j = 0; j < NR; ++j)
      bq[j] = *(const bf16x8*)&lb[(wcol + j * 16 + l15) * 32 + quad * 8];
    asm volatile("s_waitcnt lgkmcnt(0)" ::: "memory");  // reads retired
    __builtin_amdgcn_s_setprio(1);
#pragma unroll
    for (int i = 0; i < MR; ++i)
#pragma unroll
      for (int j = 0; j < NR; ++j)
        acc[i][j] = __builtin_amdgcn_mfma_f32_16x16x32_bf16(
            af[i], bq[j], acc[i][j], 0, 0, 0);
    __builtin_amdgcn_s_setprio(0);
  };

  for (int t = 0; t < NT - 2; ++t) body(t, IC<2 * L>{}, t + 3 < NT);
  body(NT - 2, IC<L>{}, false);
  body(NT - 1, IC<0>{}, false);
}

// ---------------- fused QKV GEMM -------------------------------------------
// grid (32, 24): x = m-tile (256 rows), y = which*8 + n-tile (128 cols).
__global__ __launch_bounds__(512, 2) void gemm_qkv(
    const bf16* __restrict__ Xb, const bf16* __restrict__ Wb3,
    const float* __restrict__ bq, const float* __restrict__ bk,
    const float* __restrict__ bv, bf16* __restrict__ QK,
    bf16* __restrict__ Vt) {
  __shared__ __align__(16) bf16 lds[4 * 384 * 32];  // 96 KiB
  const int which = blockIdx.y >> 3;
  const int n0 = (blockIdx.y & 7) * 128;
  const int m0 = blockIdx.x * 256;
  const bf16* Ag = Xb + (size_t)m0 * 1024;
  const bf16* Bg = Wb3 + (size_t)which * 1048576 + (size_t)n0 * 1024;
  const float* bias = (which == 0) ? bq : ((which == 1) ? bk : bv);

  f32x4 acc[4][4];
#pragma unroll
  for (int i = 0; i < 4; ++i)
#pragma unroll
    for (int j = 0; j < 4; ++j) acc[i][j] = f32x4{0.f, 0.f, 0.f, 0.f};

  kloop<256, 128, 4, 2, 32>(Ag, Bg, 1024, lds, acc);

  const int lane = threadIdx.x & 63, wave = threadIdx.x >> 6;
  const int l15 = lane & 15, quad = lane >> 4;
  const int wrow = (wave >> 1) * 64, wcol = (wave & 1) * 64;

  // C/D layout: col = lane&15, row = quad*4 + reg [m89/m91]
  if (which < 2) {
    bf16* C = QK + (size_t)which * (size_t)(8192 * 1024);
#pragma unroll
    for (int i = 0; i < 4; ++i) {
      const int r = m0 + wrow + i * 16 + quad * 4;
#pragma unroll
      for (int j = 0; j < 4; ++j) {
        const int c = n0 + wcol + j * 16 + l15;
        const float bvv = bias[c];
        f32x4 v = acc[i][j];
#pragma unroll
        for (int reg = 0; reg < 4; ++reg)
          C[(size_t)(r + reg) * 1024 + c] = (bf16)(v[reg] + bvv);
      }
    }
  } else {
#pragma unroll
    for (int i = 0; i < 4; ++i) {
      const int r = m0 + wrow + i * 16 + quad * 4;  // b*4096+s
      const int b = r >> 12, s = r & 4095;
#pragma unroll
      for (int j = 0; j < 4; ++j) {
        const int c = n0 + wcol + j * 16 + l15;  // h
        const float bvv = bias[c];
        f32x4 v = acc[i][j];
        bf16x4 o;
#pragma unroll
        for (int reg = 0; reg < 4; ++reg) o[reg] = (bf16)(v[reg] + bvv);
        *(bf16x4*)&Vt[((size_t)(b * 1024 + c)) * 4096 + s] = o;
      }
    }
  }
}

// ---------------- scores GEMM + fused exp/mask/row-sum ---------------------
// P[m,k] = exp(Q[m,:]·K[k,:] / 32) (0 where mask==0), unnormalized.
// grid (32, 16): x = m-tile (256), y = n-tile (256).
__global__ __launch_bounds__(512, 2) void gemm_scores(
    const bf16* __restrict__ Q, const bf16* __restrict__ Kb,
    const int* __restrict__ mask, bf16* __restrict__ P,
    float* __restrict__ row_sum) {
  __shared__ __align__(16) bf16 lds[4 * 512 * 32];  // 128 KiB
  const int m0 = blockIdx.x * 256;
  const int n0 = blockIdx.y * 256;
  const int batch = m0 >> 12;
  const bf16* Ag = Q + (size_t)m0 * 1024;
  const bf16* Bg = Kb + (size_t)batch * (size_t)(4096 * 1024) +
                   (size_t)n0 * 1024;

  f32x4 acc[8][4];
#pragma unroll
  for (int i = 0; i < 8; ++i)
#pragma unroll
    for (int j = 0; j < 4; ++j) acc[i][j] = f32x4{0.f, 0.f, 0.f, 0.f};

  kloop<256, 256, 2, 4, 32>(Ag, Bg, 1024, lds, acc);

  const int lane = threadIdx.x & 63, wave = threadIdx.x >> 6;
  const int l15 = lane & 15, quad = lane >> 4;
  const int wrow = (wave >> 2) * 128, wcol = (wave & 3) * 64;

  // Epilogue: e = exp(score/32) (masked), store bf16, atomic row sums.
#pragma unroll
  for (int i = 0; i < 8; ++i) {
    const int r = m0 + wrow + i * 16 + quad * 4;
    f32x4 rsum = f32x4{0.f, 0.f, 0.f, 0.f};
#pragma unroll
    for (int j = 0; j < 4; ++j) {
      const int c = n0 + wcol + j * 16 + l15;
      f32x4 v = acc[i][j];
#pragma unroll
      for (int reg = 0; reg < 4; ++reg) {
        float e = __expf(v[reg] * 0.03125f);
        if (mask[(size_t)(r + reg) * 4096 + c] == 0) e = 0.f;
        P[(size_t)(r + reg) * 4096 + c] = (bf16)e;
        rsum[reg] += e;
      }
    }
    // reduce across the 16 lanes of the quad (l15 bits 0..3)
#pragma unroll
    for (int off = 1; off < 16; off <<= 1) {
#pragma unroll
      for (int reg = 0; reg < 4; ++reg)
        rsum[reg] += __shfl_xor(rsum[reg], off);
    }
    if (l15 == 0) {
#pragma unroll
      for (int reg = 0; reg < 4; ++reg)
        atomicAdd(&row_sum[r + reg], rsum[reg]);
    }
  }
}

// ---------------- PV GEMM with 1/row_sum epilogue --------------------------
// out[m,h] = (P[m,:]·Vt[h,:]) / row_sum[m].  grid (32, 8).
__global__ __launch_bounds__(512, 2) void gemm_pv(
    const bf16* __restrict__ Pm, const bf16* __restrict__ Vt,
    const float* __restrict__ row_sum, float* __restrict__ C) {
  __shared__ __align__(16) bf16 lds[4 * 384 * 32];  // 96 KiB
  const int m0 = blockIdx.x * 256;
  const int n0 = blockIdx.y * 128;
  const int batch = m0 >> 12;
  const bf16* Ag = Pm + (size_t)m0 * 4096;
  const bf16* Bg = Vt + ((size_t)batch * 1024 + n0) * 4096;

  f32x4 acc[4][4];
#pragma unroll
  for (int i = 0; i < 4; ++i)
#pragma unroll
    for (int j = 0; j < 4; ++j) acc[i][j] = f32x4{0.f, 0.f, 0.f, 0.f};

  kloop<256, 128, 4, 2, 128>(Ag, Bg, 4096, lds, acc);

  const int lane = threadIdx.x & 63, wave = threadIdx.x >> 6;
  const int l15 = lane & 15, quad = lane >> 4;
  const int wrow = (wave >> 1) * 64, wcol = (wave & 1) * 64;

#pragma unroll
  for (int i = 0; i < 4; ++i) {
    const int r = m0 + wrow + i * 16 + quad * 4;
    const f32x4 rs = *(const f32x4*)&row_sum[r];
    f32x4 inv;
#pragma unroll
    for (int reg = 0; reg < 4; ++reg) inv[reg] = 1.0f / rs[reg];
#pragma unroll
    for (int j = 0; j < 4; ++j) {
      const int c = n0 + wcol + j * 16 + l15;
      f32x4 v = acc[i][j];
#pragma unroll
      for (int reg = 0; reg < 4; ++reg)
        C[(size_t)(r + reg) * 1024 + c] = v[reg] * inv[reg];
    }
  }
}

extern "C" void kernel_launch(void* const* d_in, const int* in_sizes, int n_in,
                              void* d_out, int out_size, void* d_ws,
                              size_t ws_size, hipStream_t stream) {
  const float* X   = (const float*)d_in[0];
  const int* mask  = (const int*)d_in[1];
  const float* Wq  = (const float*)d_in[2];
  const float* bq  = (const float*)d_in[3];
  const float* Wk  = (const float*)d_in[4];
  const float* bk  = (const float*)d_in[5];
  const float* Wv  = (const float*)d_in[6];
  const float* bv  = (const float*)d_in[7];
  float* out = (float*)d_out;

  // ws layout (128 MiB): [0,16M) Q  [16M,32M) K  [32M,48M) X_bf
  //   [48M,64M) Vt  [64M,128M) Sc/P (first 6 MiB aliased by W_bf).
  //   row_sum (32 KB) aliases X_bf (dead after gemm_qkv).
  const size_t QKV_ELEMS = (size_t)8192 * 1024;
  bf16* Q    = (bf16*)d_ws;
  bf16* Kb   = Q + QKV_ELEMS;
  bf16* X_bf = Kb + QKV_ELEMS;
  bf16* Vt   = X_bf + QKV_ELEMS;
  bf16* Sc   = Vt + QKV_ELEMS;
  bf16* W_bf = Sc;
  float* row_sum = (float*)X_bf;  // 8192 floats

  cvt_f32_bf16<<<dim3(4096), dim3(256), 0, stream>>>(X, X_bf, 8388608);
  cvt_w3<<<dim3(1536), dim3(256), 0, stream>>>(Wq, Wk, Wv, W_bf);
  gemm_qkv<<<dim3(32, 24), dim3(512), 0, stream>>>(X_bf, W_bf, bq, bk, bv, Q,
                                                   Vt);
  hipMemsetAsync(row_sum, 0, 8192 * sizeof(float), stream);
  // P = exp(QK^T/32) masked, unnormalized; row sums via atomics
  gemm_scores<<<dim3(32, 16), dim3(512), 0, stream>>>(Q, Kb, mask, Sc,
                                                      row_sum);
  // out = (P @ V) / row_sum
  gemm_pv<<<dim3(32, 8), dim3(512), 0, stream>>>(Sc, Vt, row_sum, out);
}

// Round 2
// 434.296 us; speedup vs baseline: 1.0182x; 1.0182x over previous
//
#include <hip/hip_runtime.h>
#include <stdint.h>

// SelfAttention B=2,S=4096,E=1024,H=1024. f32 in, f32 out, bf16 MFMA inside.
// R9: m201-style 8-phase schedule for all three GEMMs. BM=256, BK=64,
//     2 LDS buffers; per phase: {ds_read subtile | stage 1 half-tile
//     (2x global_load_lds) | barrier | lgkmcnt(0) | setprio(1) 16 MFMA
//     setprio(0) | [vmcnt(6|4) at each K-tile's LAST phase, before the end
//     barrier] | barrier}. Half-tiles: B-lo, B-hi, A-even-stripes,
//     A-odd-stripes; 7 halves prologued, 8 staged/iter (256-wide B) or
//     5 + 6/iter (128-wide B), 3(2) halves in flight at each vmcnt.
//     R7's measured-zero-conflict XOR swizzle restored (pre-swizzled global
//     source + ^(l15&7) on ds_read; 64-elem rows).
// R8 post-mortem: coarse per-tile phases + 64B rows = 6.3e6 bank conflicts,
//     MfmaUtil 21% (m196: coarse split without fine interleave is null).

typedef __bf16 bf16;
typedef __attribute__((ext_vector_type(4))) __bf16 bf16x4;
typedef __attribute__((ext_vector_type(8))) __bf16 bf16x8;
typedef __attribute__((ext_vector_type(4))) float f32x4;

__device__ __forceinline__ void g2l16(const void* g, void* l) {
  __builtin_amdgcn_global_load_lds(
      (const __attribute__((address_space(1))) uint32_t*)g,
      (__attribute__((address_space(3))) uint32_t*)l, 16, 0, 0);
}

template <int V> struct IC { static constexpr int value = V; };

__device__ __forceinline__ void waitvm_rt(int vm) {
  if (vm == 6) asm volatile("s_waitcnt vmcnt(6)" ::: "memory");
  else if (vm == 4) asm volatile("s_waitcnt vmcnt(4)" ::: "memory");
  else if (vm == 0) asm volatile("s_waitcnt vmcnt(0)" ::: "memory");
}

// ---------------- f32 -> bf16 converters -----------------------------------
__global__ __launch_bounds__(256) void cvt_f32_bf16(
    const float* __restrict__ src, bf16* __restrict__ dst, int n) {
  const int i = (blockIdx.x * 256 + threadIdx.x) * 8;
  if (i >= n) return;
  f32x4 a = *(const f32x4*)(src + i);
  f32x4 b = *(const f32x4*)(src + i + 4);
  bf16x8 o;
#pragma unroll
  for (int e = 0; e < 4; ++e) { o[e] = (bf16)a[e]; o[4 + e] = (bf16)b[e]; }
  *(bf16x8*)(dst + i) = o;
}

__global__ __launch_bounds__(256) void cvt_w3(
    const float* __restrict__ Wq, const float* __restrict__ Wk,
    const float* __restrict__ Wv, bf16* __restrict__ dst) {
  const int i = (blockIdx.x * 256 + threadIdx.x) * 8;
  const int seg = i >> 20;
  const int off = i & 1048575;
  const float* src = (seg == 0) ? Wq : (seg == 1) ? Wk : Wv;
  f32x4 a = *(const f32x4*)(src + off);
  f32x4 b = *(const f32x4*)(src + off + 4);
  bf16x8 o;
#pragma unroll
  for (int e = 0; e < 4; ++e) { o[e] = (bf16)a[e]; o[4 + e] = (bf16)b[e]; }
  *(bf16x8*)(dst + i) = o;
}

// ======================= kloop256: BM=256 x BN=256, BK=64 ==================
// 8 waves 2M x 4N; wave tile 128x64 (MR=8, NR=4). 4 phases per K-tile
// (phase q computes M-quarter q = frags 2q,2q+1, both k-halves, 16 MFMA).
// LDS buffer b: A[256][64] at b*32768, B[256][64] at +16384 (elems).
// Chunk c of row r holds global chunk c^(r&7) (R7 zero-conflict swizzle).
// Half-tiles: 0=B rows 0-127, 1=B rows 128-255 (B fully read at phase 0),
// 2=A rows {0-63,128-191} (read by phases 0,1), 3=A rows {64-127,192-255}
// (read by phases 2,3). Stage slots (steady iter, tiles t0,t1):
//   ph0:(t1,3) ph1:(t0+2,0) ph2:(t0+2,1) ph3:(t0+2,2)+vmcnt(6)
//   ph4:(t0+2,3) ph5:(t0+3,0) ph6:(t0+3,1) ph7:(t0+3,2)+vmcnt(6)
// Each stage lands only after the end-barrier of the phase that retires all
// waves' reads of that region; vmcnt sits BEFORE the tile-boundary barrier
// so every wave's loads for the next tile are proven landed for ALL waves.
template <int NT>
__device__ __forceinline__ void kloop256(
    const bf16* __restrict__ Ag, const bf16* __restrict__ Bg, const int KA,
    const int KB, bf16* lds, f32x4 (&acc)[8][4]) {
  const int tid = threadIdx.x;
  const int lane = tid & 63, wave = tid >> 6;
  const int l15 = lane & 15, quad = lane >> 4;
  const int wrow = (wave >> 2) * 128;
  const int wcol = (wave & 3) * 64;
  const int srow = tid >> 3;                    // 0..63
  const int scol = ((tid & 7) ^ (srow & 7)) * 8;  // pre-swizzled source col
  const int swz = l15 & 7;

  auto stg = [&](int t, int h) {
    bf16* base = lds + (t & 1) * 32768;
    if (h == 0) {            // B rows 0-127
      const bf16* g = Bg + (size_t)srow * KB + t * 64 + scol;
      g2l16(g, base + 16384 + tid * 8);
      g2l16(g + (size_t)64 * KB, base + 16384 + tid * 8 + 4096);
    } else if (h == 1) {     // B rows 128-255
      const bf16* g = Bg + (size_t)(128 + srow) * KB + t * 64 + scol;
      g2l16(g, base + 24576 + tid * 8);
      g2l16(g + (size_t)64 * KB, base + 24576 + tid * 8 + 4096);
    } else if (h == 2) {     // A rows {0-63, 128-191}
      const bf16* g = Ag + (size_t)srow * KA + t * 64 + scol;
      g2l16(g, base + tid * 8);
      g2l16(g + (size_t)128 * KA, base + tid * 8 + 8192);
    } else {                 // A rows {64-127, 192-255}
      const bf16* g = Ag + (size_t)(64 + srow) * KA + t * 64 + scol;
      g2l16(g, base + 4096 + tid * 8);
      g2l16(g + (size_t)128 * KA, base + 4096 + tid * 8 + 8192);
    }
  };

  bf16x8 bq[2][4];
  auto phase = [&](int t, auto qc, int st, int sh, bool ds, int vm) {
    constexpr int q = decltype(qc)::value;
    bf16* base = lds + (t & 1) * 32768;
    bf16x8 af[2][2];
#pragma unroll
    for (int i = 0; i < 2; ++i)
#pragma unroll
      for (int ks = 0; ks < 2; ++ks)
        af[i][ks] = *(const bf16x8*)&base[
            (wrow + (2 * q + i) * 16 + l15) * 64 + ((ks * 4 + quad) ^ swz) * 8];
    if constexpr (q == 0) {
#pragma unroll
      for (int j = 0; j < 4; ++j)
#pragma unroll
        for (int ks = 0; ks < 2; ++ks)
          bq[ks][j] = *(const bf16x8*)&base[16384 +
              (wcol + j * 16 + l15) * 64 + ((ks * 4 + quad) ^ swz) * 8];
    }
    if (ds) stg(st, sh);
    __builtin_amdgcn_s_barrier();
    asm volatile("s_waitcnt lgkmcnt(0)" ::: "memory");
    __builtin_amdgcn_sched_barrier(0);
    __builtin_amdgcn_s_setprio(1);
#pragma unroll
    for (int ks = 0; ks < 2; ++ks)
#pragma unroll
      for (int i = 0; i < 2; ++i)
#pragma unroll
        for (int j = 0; j < 4; ++j)
          acc[2 * q + i][j] = __builtin_amdgcn_mfma_f32_16x16x32_bf16(
              af[i][ks], bq[ks][j], acc[2 * q + i][j], 0, 0, 0);
    __builtin_amdgcn_s_setprio(0);
    waitvm_rt(vm);
    __builtin_amdgcn_s_barrier();
  };

  // prologue: 7 half-tiles (14 loads); vmcnt(6) -> tile 0 fully landed.
  stg(0, 0); stg(0, 1); stg(0, 2); stg(0, 3);
  stg(1, 0); stg(1, 1); stg(1, 2);
  asm volatile("s_waitcnt vmcnt(6)" ::: "memory");
  __builtin_amdgcn_s_barrier();

  constexpr int NI = NT / 2;
#pragma unroll 1
  for (int u = 0; u < NI; ++u) {
    const int t0 = 2 * u, t1 = t0 + 1;
    const bool nl = (u + 1 < NI);
    phase(t0, IC<0>{}, t1, 3, true, -1);
    phase(t0, IC<1>{}, t0 + 2, 0, nl, -1);
    phase(t0, IC<2>{}, t0 + 2, 1, nl, -1);
    phase(t0, IC<3>{}, t0 + 2, 2, nl, nl ? 6 : 0);
    phase(t1, IC<0>{}, t0 + 2, 3, nl, -1);
    phase(t1, IC<1>{}, t0 + 3, 0, nl, -1);
    phase(t1, IC<2>{}, t0 + 3, 1, nl, -1);
    phase(t1, IC<3>{}, t0 + 3, 2, nl, nl ? 6 : -1);
  }
}

// ======================= kloop128: BM=256 x BN=128, BK=64 ==================
// 8 waves 4M x 2N; wave tile 64x64 (MR=4, NR=4). 2 phases per K-tile
// (phase mh computes frags 2mh,2mh+1, both k-halves, 16 MFMA).
// LDS buffer b: A[256][64] at b*24576, B[128][64] at +16384 (elems).
// Half-tiles: 0=B (full), 1=A rows (row>>5)&1==0 {0-31,64-95,128-159,192-223}
// (read at phase 0), 2=A rows odd 32-blocks (read at phase 1).
// Stage slots (steady iter): ph0:(t1,2) ph1:(t0+2,0)+(t0+2,1)+vmcnt(4)
//                            ph2:(t0+2,2) ph3:(t0+3,0)+(t0+3,1)+vmcnt(4)
template <int NT>
__device__ __forceinline__ void kloop128(
    const bf16* __restrict__ Ag, const bf16* __restrict__ Bg, const int KA,
    const int KB, bf16* lds, f32x4 (&acc)[4][4]) {
  const int tid = threadIdx.x;
  const int lane = tid & 63, wave = tid >> 6;
  const int l15 = lane & 15, quad = lane >> 4;
  const int wrow = (wave >> 1) * 64;
  const int wcol = (wave & 1) * 64;
  const int srow = tid >> 3;
  const int scol = ((tid & 7) ^ (srow & 7)) * 8;
  const int swz = l15 & 7;
  const int s5 = srow >> 5;       // wave-uniform (0 for waves 0-3, 1 for 4-7)
  const int r31 = srow & 31;

  auto stg = [&](int t, int h) {
    bf16* base = lds + (t & 1) * 24576;
    if (h == 0) {            // B rows 0-127
      const bf16* g = Bg + (size_t)srow * KB + t * 64 + scol;
      g2l16(g, base + 16384 + tid * 8);
      g2l16(g + (size_t)64 * KB, base + 16384 + tid * 8 + 4096);
    } else {                 // A stripes: blocks {0,2,4,6} (h=1) / {1,3,5,7}
      const int r0 = s5 * 64 + ((h == 2) ? 32 : 0) + r31;
      const bf16* g = Ag + (size_t)r0 * KA + t * 64 + scol;
      bf16* d = base + ((h == 2) ? 2048 : 0) + s5 * 4096 + r31 * 64 +
                (tid & 7) * 8;
      g2l16(g, d);
      g2l16(g + (size_t)128 * KA, d + 8192);
    }
  };

  bf16x8 bq[2][4];
  auto phase = [&](int t, auto mhc, int st1, int sh1, int st2, int sh2,
                   bool ds, int vm) {
    constexpr int mh = decltype(mhc)::value;
    bf16* base = lds + (t & 1) * 24576;
    bf16x8 af[2][2];
#pragma unroll
    for (int i = 0; i < 2; ++i)
#pragma unroll
      for (int ks = 0; ks < 2; ++ks)
        af[i][ks] = *(const bf16x8*)&base[
            (wrow + (2 * mh + i) * 16 + l15) * 64 +
            ((ks * 4 + quad) ^ swz) * 8];
    if constexpr (mh == 0) {
#pragma unroll
      for (int j = 0; j < 4; ++j)
#pragma unroll
        for (int ks = 0; ks < 2; ++ks)
          bq[ks][j] = *(const bf16x8*)&base[16384 +
              (wcol + j * 16 + l15) * 64 + ((ks * 4 + quad) ^ swz) * 8];
    }
    if (ds) { stg(st1, sh1); if (sh2 >= 0) stg(st2, sh2); }
    __builtin_amdgcn_s_barrier();
    asm volatile("s_waitcnt lgkmcnt(0)" ::: "memory");
    __builtin_amdgcn_sched_barrier(0);
    __builtin_amdgcn_s_setprio(1);
#pragma unroll
    for (int ks = 0; ks < 2; ++ks)
#pragma unroll
      for (int i = 0; i < 2; ++i)
#pragma unroll
        for (int j = 0; j < 4; ++j)
          acc[2 * mh + i][j] = __builtin_amdgcn_mfma_f32_16x16x32_bf16(
              af[i][ks], bq[ks][j], acc[2 * mh + i][j], 0, 0, 0);
    __builtin_amdgcn_s_setprio(0);
    waitvm_rt(vm);
    __builtin_amdgcn_s_barrier();
  };

  // prologue: 5 half-tiles (10 loads); vmcnt(4) -> tile 0 fully landed.
  stg(0, 0); stg(0, 1); stg(0, 2);
  stg(1, 0); stg(1, 1);
  asm volatile("s_waitcnt vmcnt(4)" ::: "memory");
  __builtin_amdgcn_s_barrier();

  constexpr int NI = NT / 2;
#pragma unroll 1
  for (int u = 0; u < NI; ++u) {
    const int t0 = 2 * u, t1 = t0 + 1;
    const bool nl = (u + 1 < NI);
    phase(t0, IC<0>{}, t1, 2, -1, -1, true, -1);
    phase(t0, IC<1>{}, t0 + 2, 0, t0 + 2, 1, nl, nl ? 4 : 0);
    phase(t1, IC<0>{}, t0 + 2, 2, -1, -1, nl, -1);
    phase(t1, IC<1>{}, t0 + 3, 0, t0 + 3, 1, nl, nl ? 4 : -1);
  }
}

// ---------------- fused QKV GEMM -------------------------------------------
// grid (32, 24): x = m-tile (256 rows), y = which*8 + n-tile (128 cols).
__global__ __launch_bounds__(512, 2) void gemm_qkv(
    const bf16* __restrict__ Xb, const bf16* __restrict__ Wb3,
    const float* __restrict__ bq, const float* __restrict__ bk,
    const float* __restrict__ bv, bf16* __restrict__ QK,
    bf16* __restrict__ Vt) {
  __shared__ __align__(16) bf16 lds[2 * 24576];  // 96 KiB
  const int which = blockIdx.y >> 3;
  const int n0 = (blockIdx.y & 7) * 128;
  const int m0 = blockIdx.x * 256;
  const bf16* Ag = Xb + (size_t)m0 * 1024;
  const bf16* Bg = Wb3 + (size_t)which * 1048576 + (size_t)n0 * 1024;
  const float* bias = (which == 0) ? bq : ((which == 1) ? bk : bv);

  f32x4 acc[4][4];
#pragma unroll
  for (int i = 0; i < 4; ++i)
#pragma unroll
    for (int j = 0; j < 4; ++j) acc[i][j] = f32x4{0.f, 0.f, 0.f, 0.f};

  kloop128<16>(Ag, Bg, 1024, 1024, lds, acc);

  const int lane = threadIdx.x & 63, wave = threadIdx.x >> 6;
  const int l15 = lane & 15, quad = lane >> 4;
  const int wrow = (wave >> 1) * 64, wcol = (wave & 1) * 64;

  // C/D layout: col = lane&15, row = quad*4 + reg [m89/m91]
  if (which < 2) {
    bf16* C = QK + (size_t)which * (size_t)(8192 * 1024);
#pragma unroll
    for (int i = 0; i < 4; ++i) {
      const int r = m0 + wrow + i * 16 + quad * 4;
#pragma unroll
      for (int j = 0; j < 4; ++j) {
        const int c = n0 + wcol + j * 16 + l15;
        const float bvv = bias[c];
        f32x4 v = acc[i][j];
#pragma unroll
        for (int reg = 0; reg < 4; ++reg)
          C[(size_t)(r + reg) * 1024 + c] = (bf16)(v[reg] + bvv);
      }
    }
  } else {
#pragma unroll
    for (int i = 0; i < 4; ++i) {
      const int r = m0 + wrow + i * 16 + quad * 4;  // b*4096+s
      const int b = r >> 12, s = r & 4095;
#pragma unroll
      for (int j = 0; j < 4; ++j) {
        const int c = n0 + wcol + j * 16 + l15;  // h
        const float bvv = bias[c];
        f32x4 v = acc[i][j];
        bf16x4 o;
#pragma unroll
        for (int reg = 0; reg < 4; ++reg) o[reg] = (bf16)(v[reg] + bvv);
        *(bf16x4*)&Vt[((size_t)(b * 1024 + c)) * 4096 + s] = o;
      }
    }
  }
}

// ---------------- scores GEMM + fused exp/mask/row-sum ---------------------
// P[m,k] = exp(Q[m,:]·K[k,:] / 32) (0 where mask==0), unnormalized.
// grid (32, 16): x = m-tile (256), y = n-tile (256).
__global__ __launch_bounds__(512, 2) void gemm_scores(
    const bf16* __restrict__ Q, const bf16* __restrict__ Kb,
    const int* __restrict__ mask, bf16* __restrict__ P,
    float* __restrict__ row_sum) {
  __shared__ __align__(16) bf16 lds[2 * 32768];  // 128 KiB
  const int m0 = blockIdx.x * 256;
  const int n0 = blockIdx.y * 256;
  const int batch = m0 >> 12;
  const bf16* Ag = Q + (size_t)m0 * 1024;
  const bf16* Bg = Kb + (size_t)batch * (size_t)(4096 * 1024) +
                   (size_t)n0 * 1024;

  f32x4 acc[8][4];
#pragma unroll
  for (int i = 0; i < 8; ++i)
#pragma unroll
    for (int j = 0; j < 4; ++j) acc[i][j] = f32x4{0.f, 0.f, 0.f, 0.f};

  kloop256<16>(Ag, Bg, 1024, 1024, lds, acc);

  const int lane = threadIdx.x & 63, wave = threadIdx.x >> 6;
  const int l15 = lane & 15, quad = lane >> 4;
  const int wrow = (wave >> 2) * 128, wcol = (wave & 3) * 64;

  // Epilogue: e = exp(score/32) (masked), store bf16, atomic row sums.
#pragma unroll
  for (int i = 0; i < 8; ++i) {
    const int r = m0 + wrow + i * 16 + quad * 4;
    f32x4 rsum = f32x4{0.f, 0.f, 0.f, 0.f};
#pragma unroll
    for (int j = 0; j < 4; ++j) {
      const int c = n0 + wcol + j * 16 + l15;
      f32x4 v = acc[i][j];
#pragma unroll
      for (int reg = 0; reg < 4; ++reg) {
        float e = __expf(v[reg] * 0.03125f);
        if (mask[(size_t)(r + reg) * 4096 + c] == 0) e = 0.f;
        P[(size_t)(r + reg) * 4096 + c] = (bf16)e;
        rsum[reg] += e;
      }
    }
    // reduce across the 16 lanes of the quad (l15 bits 0..3)
#pragma unroll
    for (int off = 1; off < 16; off <<= 1) {
#pragma unroll
      for (int reg = 0; reg < 4; ++reg)
        rsum[reg] += __shfl_xor(rsum[reg], off);
    }
    if (l15 == 0) {
#pragma unroll
      for (int reg = 0; reg < 4; ++reg)
        atomicAdd(&row_sum[r + reg], rsum[reg]);
    }
  }
}

// ---------------- PV GEMM with 1/row_sum epilogue --------------------------
// out[m,h] = (P[m,:]·Vt[h,:]) / row_sum[m].  grid (32, 8).
__global__ __launch_bounds__(512, 2) void gemm_pv(
    const bf16* __restrict__ Pm, const bf16* __restrict__ Vt,
    const float* __restrict__ row_sum, float* __restrict__ C) {
  __shared__ __align__(16) bf16 lds[2 * 24576];  // 96 KiB
  const int m0 = blockIdx.x * 256;
  const int n0 = blockIdx.y * 128;
  const int batch = m0 >> 12;
  const bf16* Ag = Pm + (size_t)m0 * 4096;
  const bf16* Bg = Vt + ((size_t)batch * 1024 + n0) * 4096;

  f32x4 acc[4][4];
#pragma unroll
  for (int i = 0; i < 4; ++i)
#pragma unroll
    for (int j = 0; j < 4; ++j) acc[i][j] = f32x4{0.f, 0.f, 0.f, 0.f};

  kloop128<64>(Ag, Bg, 4096, 4096, lds, acc);

  const int lane = threadIdx.x & 63, wave = threadIdx.x >> 6;
  const int l15 = lane & 15, quad = lane >> 4;
  const int wrow = (wave >> 1) * 64, wcol = (wave & 1) * 64;

#pragma unroll
  for (int i = 0; i < 4; ++i) {
    const int r = m0 + wrow + i * 16 + quad * 4;
    const f32x4 rs = *(const f32x4*)&row_sum[r];
    f32x4 inv;
#pragma unroll
    for (int reg = 0; reg < 4; ++reg) inv[reg] = 1.0f / rs[reg];
#pragma unroll
    for (int j = 0; j < 4; ++j) {
      const int c = n0 + wcol + j * 16 + l15;
      f32x4 v = acc[i][j];
#pragma unroll
      for (int reg = 0; reg < 4; ++reg)
        C[(size_t)(r + reg) * 1024 + c] = v[reg] * inv[reg];
    }
  }
}

extern "C" void kernel_launch(void* const* d_in, const int* in_sizes, int n_in,
                              void* d_out, int out_size, void* d_ws,
                              size_t ws_size, hipStream_t stream) {
  const float* X   = (const float*)d_in[0];
  const int* mask  = (const int*)d_in[1];
  const float* Wq  = (const float*)d_in[2];
  const float* bq  = (const float*)d_in[3];
  const float* Wk  = (const float*)d_in[4];
  const float* bk  = (const float*)d_in[5];
  const float* Wv  = (const float*)d_in[6];
  const float* bv  = (const float*)d_in[7];
  float* out = (float*)d_out;

  // ws layout (128 MiB): [0,16M) Q  [16M,32M) K  [32M,48M) X_bf
  //   [48M,64M) Vt  [64M,128M) Sc/P (first 6 MiB aliased by W_bf).
  //   row_sum (32 KB) aliases X_bf (dead after gemm_qkv).
  const size_t QKV_ELEMS = (size_t)8192 * 1024;
  bf16* Q    = (bf16*)d_ws;
  bf16* Kb   = Q + QKV_ELEMS;
  bf16* X_bf = Kb + QKV_ELEMS;
  bf16* Vt   = X_bf + QKV_ELEMS;
  bf16* Sc   = Vt + QKV_ELEMS;
  bf16* W_bf = Sc;
  float* row_sum = (float*)X_bf;  // 8192 floats

  cvt_f32_bf16<<<dim3(4096), dim3(256), 0, stream>>>(X, X_bf, 8388608);
  cvt_w3<<<dim3(1536), dim3(256), 0, stream>>>(Wq, Wk, Wv, W_bf);
  gemm_qkv<<<dim3(32, 24), dim3(512), 0, stream>>>(X_bf, W_bf, bq, bk, bv, Q,
                                                   Vt);
  hipMemsetAsync(row_sum, 0, 8192 * sizeof(float), stream);
  // P = exp(QK^T/32) masked, unnormalized; row sums via atomics
  gemm_scores<<<dim3(32, 16), dim3(512), 0, stream>>>(Q, Kb, mask, Sc,
                                                      row_sum);
  // out = (P @ V) / row_sum
  gemm_pv<<<dim3(32, 8), dim3(512), 0, stream>>>(Sc, Vt, row_sum, out);
}